// Round 13
// baseline (83.789 us; speedup 1.0000x reference)
//
#include <hip/hip_runtime.h>

// Capsule routing, MI355X. B=2048, I=64, O=32, DI=DO=16, 3 iters.
// R12 status: conflicts fixed (strided-8 phase model verified), 83 us,
// VALU 62% / DS ~65% busy at only 16 waves/CU (LDS 65KB -> 2 blocks/CU):
// latency-bound. R13: LDS diet -> 3 blocks/CU (24 waves, +50%):
//   x staged in 4-b HALF-tiles (16.9 KB) instead of 8-b (33.8 KB);
//   LDS = p 32 KB + x_t 16.9 KB = 49,664 B. A-phase runs twice per
//   sub-round (halves h=0,1) with identical per-instr patterns; B-phase
//   (8-b, p[16]) unchanged. 4 barriers/sub-round; T14 split staging keeps
//   every half's global loads issued a full phase ahead.
// VGPR budget: wq 32 + p 16 + 2x2 float4 staging + addr ~= 55-64.
//   MUST stay <=64 (R9: >64 halves residency).
// x_t layout (quad-skewed, conflict-free for strided-8 b128 phases):
//   X(b',i,e) = b'*1056 + 16i + 4*(i>>3) + e   (floats), b' in 0..3.
// Staging writes 2-way (free-ish); A-phase reads conflict-free;
// p write/read patterns = R12 (verified).
// Straight-line, constant-indexed arrays (R7 SROA lesson); builtin
// exp2/rcp/sqrt (|arg|<~95, no overflow); no min-wave forcing (R2/R5).

#define THREADS 512

__global__ __launch_bounds__(THREADS) void routing_kernel(
    const float* __restrict__ x,    // (B, DI, I) = (2048,16,64)
    const float* __restrict__ rw,   // (O, I, DO, DI) = (32,64,16,16)
    const float* __restrict__ ns,   // same
    float* __restrict__ out)        // (1, O, B, DO)
{
    extern __shared__ float lds[];  // [0,8192) p; [8192,12416) x_t half-tile
    float* xlds = lds + 8192;

    const int tid  = threadIdx.x;
    const int w    = tid >> 6;      // wave 0..7
    const int lane = tid & 63;      // = i in A-phase

    const int o  = blockIdx.x >> 6;   // o-major: 64 consecutive blocks share W
    const int bc = blockIdx.x & 63;   // 32-b chunk
    const int bbase = bc * 32;

    // ---- W+noise fragment: lane=i, d in {2w, 2w+1} (32 VGPR) ----
    float wq0[16], wq1[16];
    {
        const int base = (o * 64 + lane) * 256 + w * 32;
        #pragma unroll
        for (int eq = 0; eq < 4; ++eq) {
            const float4 a0 = *reinterpret_cast<const float4*>(rw + base + eq * 4);
            const float4 n0 = *reinterpret_cast<const float4*>(ns + base + eq * 4);
            wq0[4*eq+0] = a0.x + n0.x;  wq0[4*eq+1] = a0.y + n0.y;
            wq0[4*eq+2] = a0.z + n0.z;  wq0[4*eq+3] = a0.w + n0.w;
            const float4 a1 = *reinterpret_cast<const float4*>(rw + base + 16 + eq * 4);
            const float4 n1 = *reinterpret_cast<const float4*>(ns + base + 16 + eq * 4);
            wq1[4*eq+0] = a1.x + n1.x;  wq1[4*eq+1] = a1.y + n1.y;
            wq1[4*eq+2] = a1.z + n1.z;  wq1[4*eq+3] = a1.w + n1.w;
        }
    }

    // ---- precomputed LDS addresses ----
    const int d0 = 2 * w, d1 = 2 * w + 1;
    float* pw0 = lds + d0 * 64 + ((((lane >> 2) ^ (d0 & 7)) << 2) | (lane & 3));
    float* pw1 = lds + d1 * 64 + ((((lane >> 2) ^ (d1 & 7)) << 2) | (lane & 3));

    const int qB  = lane >> 4;      // i-quarter 0..3
    const int dB  = lane & 15;
    const int swz = dB & 7;
    const float4* prbase = reinterpret_cast<const float4*>(lds) + (w * 16 + dB) * 16;
    const float4* pr0 = prbase + ((4 * qB + 0) ^ swz);
    const float4* pr1 = prbase + ((4 * qB + 1) ^ swz);
    const float4* pr2 = prbase + ((4 * qB + 2) ^ swz);
    const float4* pr3 = prbase + ((4 * qB + 3) ^ swz);

    // x_t reads (A-phase): lane = i; base quad-skewed by i>>3
    const float* xrb = xlds + lane * 16 + ((lane >> 3) << 2);

    // staging: thread covers float4s (b'=b0q, rem) and (b'=b0q+2, rem)
    const int rem = tid & 255;
    const int b0q = tid >> 8;       // 0 or 1
    const int i4  = tid & 15;
    const int eS  = (tid >> 4) & 15;
    float* xwA = xlds + b0q * 1056 + i4 * 64 + ((i4 >> 1) << 2) + eS;
    float* xwB = xwA + 2112;        // b' + 2
    const float4* xsrcB = reinterpret_cast<const float4*>(x) + bbase * 256 + rem;
    const int gA = b0q * 256;       // + (s*8 + h*4)*256 per phase; +512 for b'+2

    const int outbase = (o * 2048 + bbase + w) * 16 + dB;

    // ---- prologue: stage half (s=0,h=0); issue loads for (0,1) ----
    float4 vA = xsrcB[gA];
    float4 vB = xsrcB[gA + 512];
    xwA[0] = vA.x;  xwA[16] = vA.y;  xwA[32] = vA.z;  xwA[48] = vA.w;
    xwB[0] = vB.x;  xwB[16] = vB.y;  xwB[32] = vB.z;  xwB[48] = vB.w;
    float4 wA = xsrcB[gA + 1024];   // h=1 of s=0
    float4 wB = xsrcB[gA + 1536];
    __syncthreads();                // x_t(0,0) ready

    #pragma unroll
    for (int s = 0; s < 4; ++s) {
        // ---- A-phase half h: 4 bb, p rows (h*4+bb) ----
        #define APHASE(H)                                                        \
        {                                                                        \
            _Pragma("unroll")                                                    \
            for (int bb = 0; bb < 4; ++bb) {                                     \
                const float4 v0 = *reinterpret_cast<const float4*>(xrb + bb * 1056 + 0);  \
                const float4 v1 = *reinterpret_cast<const float4*>(xrb + bb * 1056 + 4);  \
                const float4 v2 = *reinterpret_cast<const float4*>(xrb + bb * 1056 + 8);  \
                const float4 v3 = *reinterpret_cast<const float4*>(xrb + bb * 1056 + 12); \
                float a0 = 0.f, a1 = 0.f;                                        \
                a0 = fmaf(wq0[0],  v0.x, a0);  a1 = fmaf(wq1[0],  v0.x, a1);     \
                a0 = fmaf(wq0[1],  v0.y, a0);  a1 = fmaf(wq1[1],  v0.y, a1);     \
                a0 = fmaf(wq0[2],  v0.z, a0);  a1 = fmaf(wq1[2],  v0.z, a1);     \
                a0 = fmaf(wq0[3],  v0.w, a0);  a1 = fmaf(wq1[3],  v0.w, a1);     \
                a0 = fmaf(wq0[4],  v1.x, a0);  a1 = fmaf(wq1[4],  v1.x, a1);     \
                a0 = fmaf(wq0[5],  v1.y, a0);  a1 = fmaf(wq1[5],  v1.y, a1);     \
                a0 = fmaf(wq0[6],  v1.z, a0);  a1 = fmaf(wq1[6],  v1.z, a1);     \
                a0 = fmaf(wq0[7],  v1.w, a0);  a1 = fmaf(wq1[7],  v1.w, a1);     \
                a0 = fmaf(wq0[8],  v2.x, a0);  a1 = fmaf(wq1[8],  v2.x, a1);     \
                a0 = fmaf(wq0[9],  v2.y, a0);  a1 = fmaf(wq1[9],  v2.y, a1);     \
                a0 = fmaf(wq0[10], v2.z, a0);  a1 = fmaf(wq1[10], v2.z, a1);     \
                a0 = fmaf(wq0[11], v2.w, a0);  a1 = fmaf(wq1[11], v2.w, a1);     \
                a0 = fmaf(wq0[12], v3.x, a0);  a1 = fmaf(wq1[12], v3.x, a1);     \
                a0 = fmaf(wq0[13], v3.y, a0);  a1 = fmaf(wq1[13], v3.y, a1);     \
                a0 = fmaf(wq0[14], v3.z, a0);  a1 = fmaf(wq1[14], v3.z, a1);     \
                a0 = fmaf(wq0[15], v3.w, a0);  a1 = fmaf(wq1[15], v3.w, a1);     \
                pw0[((H) * 4 + bb) * 1024] = a0;                                 \
                pw1[((H) * 4 + bb) * 1024] = a1;                                 \
            }                                                                    \
        }

        APHASE(0)
        __syncthreads();            // bar1: x_t(h0) reads done

        // store h1 (loaded during A0); issue loads for (s+1, 0)
        xwA[0] = wA.x;  xwA[16] = wA.y;  xwA[32] = wA.z;  xwA[48] = wA.w;
        xwB[0] = wB.x;  xwB[16] = wB.y;  xwB[32] = wB.z;  xwB[48] = wB.w;
        if (s < 3) {
            vA = xsrcB[gA + (s + 1) * 2048];
            vB = xsrcB[gA + (s + 1) * 2048 + 512];
        }
        __syncthreads();            // bar2: x_t(h1) ready

        APHASE(1)
        __syncthreads();            // bar3: p complete, x_t(h1) reads done

        // ---- B-read: p[16] ----
        float p[16];
        {
            const float4 v0 = *pr0, v1 = *pr1, v2 = *pr2, v3 = *pr3;
            p[0]=v0.x; p[1]=v0.y; p[2]=v0.z; p[3]=v0.w;
            p[4]=v1.x; p[5]=v1.y; p[6]=v1.z; p[7]=v1.w;
            p[8]=v2.x; p[9]=v2.y; p[10]=v2.z; p[11]=v2.w;
            p[12]=v3.x; p[13]=v3.y; p[14]=v3.z; p[15]=v3.w;
        }

        // store (s+1,0); issue loads for (s+1,1)
        if (s < 3) {
            xwA[0] = vA.x;  xwA[16] = vA.y;  xwA[32] = vA.z;  xwA[48] = vA.w;
            xwB[0] = vB.x;  xwB[16] = vB.y;  xwB[32] = vB.z;  xwB[48] = vB.w;
            wA = xsrcB[gA + (s + 1) * 2048 + 1024];
            wB = xsrcB[gA + (s + 1) * 2048 + 1536];
        }

        // ---- routing iterations ----
        float t0 = (p[0]+p[1]) + (p[2]+p[3]);
        float t1 = (p[4]+p[5]) + (p[6]+p[7]);
        float t2 = (p[8]+p[9]) + (p[10]+p[11]);
        float t3 = (p[12]+p[13]) + (p[14]+p[15]);
        float part = (t0 + t1) + (t2 + t3);
        part += __shfl_xor(part, 16);
        part += __shfl_xor(part, 32);
        float sv = part * (1.0f / 64.0f);

        float sn = sv * sv;         // squash norm over d (16-lane groups)
        sn += __shfl_xor(sn, 1); sn += __shfl_xor(sn, 2);
        sn += __shfl_xor(sn, 4); sn += __shfl_xor(sn, 8);
        float factor = __builtin_amdgcn_sqrtf(sn)
                     * __builtin_amdgcn_rcpf(1.0f + sn);
        float Vsum = sv * factor;

        #pragma unroll
        for (int it = 0; it < 2; ++it) {
            const float c = Vsum * 1.44269504089f;      // log2(e)
            float e0, e1, e2, e3;
            float dd0, dd1, dd2, dd3, nn0, nn1, nn2, nn3;
            e0 = __builtin_amdgcn_exp2f(p[0] * c);
            e1 = __builtin_amdgcn_exp2f(p[1] * c);
            e2 = __builtin_amdgcn_exp2f(p[2] * c);
            e3 = __builtin_amdgcn_exp2f(p[3] * c);
            dd0 = e0; dd1 = e1; dd2 = e2; dd3 = e3;
            nn0 = e0 * p[0]; nn1 = e1 * p[1]; nn2 = e2 * p[2]; nn3 = e3 * p[3];
            e0 = __builtin_amdgcn_exp2f(p[4] * c);
            e1 = __builtin_amdgcn_exp2f(p[5] * c);
            e2 = __builtin_amdgcn_exp2f(p[6] * c);
            e3 = __builtin_amdgcn_exp2f(p[7] * c);
            dd0 += e0; dd1 += e1; dd2 += e2; dd3 += e3;
            nn0 = fmaf(e0, p[4], nn0); nn1 = fmaf(e1, p[5], nn1);
            nn2 = fmaf(e2, p[6], nn2); nn3 = fmaf(e3, p[7], nn3);
            e0 = __builtin_amdgcn_exp2f(p[8] * c);
            e1 = __builtin_amdgcn_exp2f(p[9] * c);
            e2 = __builtin_amdgcn_exp2f(p[10] * c);
            e3 = __builtin_amdgcn_exp2f(p[11] * c);
            dd0 += e0; dd1 += e1; dd2 += e2; dd3 += e3;
            nn0 = fmaf(e0, p[8], nn0);  nn1 = fmaf(e1, p[9], nn1);
            nn2 = fmaf(e2, p[10], nn2); nn3 = fmaf(e3, p[11], nn3);
            e0 = __builtin_amdgcn_exp2f(p[12] * c);
            e1 = __builtin_amdgcn_exp2f(p[13] * c);
            e2 = __builtin_amdgcn_exp2f(p[14] * c);
            e3 = __builtin_amdgcn_exp2f(p[15] * c);
            dd0 += e0; dd1 += e1; dd2 += e2; dd3 += e3;
            nn0 = fmaf(e0, p[12], nn0); nn1 = fmaf(e1, p[13], nn1);
            nn2 = fmaf(e2, p[14], nn2); nn3 = fmaf(e3, p[15], nn3);

            float den = (dd0 + dd1) + (dd2 + dd3);
            float num = (nn0 + nn1) + (nn2 + nn3);
            den += __shfl_xor(den, 16); den += __shfl_xor(den, 32);
            num += __shfl_xor(num, 16); num += __shfl_xor(num, 32);
            sv = num * __builtin_amdgcn_rcpf(den);
            sn = sv * sv;
            sn += __shfl_xor(sn, 1); sn += __shfl_xor(sn, 2);
            sn += __shfl_xor(sn, 4); sn += __shfl_xor(sn, 8);
            factor = __builtin_amdgcn_sqrtf(sn)
                   * __builtin_amdgcn_rcpf(1.0f + sn);
            Vsum += sv * factor;
        }

        if (qB == 0)
            out[outbase + s * 128] = sv * factor;       // (1,O,B,DO), b=+8 per s

        __syncthreads();            // bar4: p reads done; x_t(s+1,0) ready
    }
}

extern "C" void kernel_launch(void* const* d_in, const int* in_sizes, int n_in,
                              void* d_out, int out_size, void* d_ws, size_t ws_size,
                              hipStream_t stream) {
    const float* x  = (const float*)d_in[0];
    const float* rw = (const float*)d_in[1];
    const float* ns = (const float*)d_in[2];
    float* out = (float*)d_out;
    (void)d_ws; (void)ws_size; (void)in_sizes; (void)n_in; (void)out_size;

    const int grid = 32 * 64;       // blockIdx = o*64 + bc
    routing_kernel<<<grid, THREADS, 49664, stream>>>(x, rw, ns, out);
}

// Round 14
// 76.594 us; speedup vs baseline: 1.0939x; 1.0939x over previous
//
#include <hip/hip_runtime.h>

// Capsule routing, MI355X. B=2048, I=64, O=32, DI=DO=16, 3 iters.
// R13 neutral -> occupancy not binding; balanced VALU/DS + barrier regime.
// R14 attacks the un-hidden W prologue (~512 KB L2 cold fetch per block,
// ~30 us/CU total at NB=32):
//   * NB=64 per block (1024 blocks, 4/CU): W prologue count per CU halves.
//   * W' = rw+ns precomputed once into d_ws (2 MB, guarded by ws_size;
//     fallback reads rw+ns directly): W prologue bytes halve, adds vanish.
// Compute structure = R12 verbatim (verified: quad-skewed x_t conflict-free
// under strided-8 b128 phases; p swizzles; T14 split staging; builtins;
// straight-line constant-indexed code; no min-wave forcing).
// LDS 66,560 B: p 32 KB + x_t 33 KB -> 2 blocks/CU.

#define THREADS 512

__global__ __launch_bounds__(256) void wsum_kernel(
    const float* __restrict__ rw, const float* __restrict__ ns,
    float* __restrict__ w2)
{
    const int i = blockIdx.x * 256 + threadIdx.x;   // 131072 float4s
    const float4 a = reinterpret_cast<const float4*>(rw)[i];
    const float4 n = reinterpret_cast<const float4*>(ns)[i];
    float4 r;
    r.x = a.x + n.x;  r.y = a.y + n.y;  r.z = a.z + n.z;  r.w = a.w + n.w;
    reinterpret_cast<float4*>(w2)[i] = r;
}

template <bool PRE>
__global__ __launch_bounds__(THREADS) void routing_kernel(
    const float* __restrict__ x,    // (B, DI, I) = (2048,16,64)
    const float* __restrict__ rw,   // PRE ? W'=(rw+ns) : rw   (O,I,DO,DI)
    const float* __restrict__ ns,   // unused if PRE
    float* __restrict__ out)        // (1, O, B, DO)
{
    extern __shared__ float lds[];  // [0,8192) p; [8192,16640) x_t (skewed)
    float* xlds = lds + 8192;       // X(b',i,e) = b'*1056 + 16i + 4*(i>>3) + e

    const int tid  = threadIdx.x;
    const int w    = tid >> 6;      // wave 0..7
    const int lane = tid & 63;      // = i in A-phase

    const int o  = blockIdx.x >> 5;   // o-major: 32 consecutive blocks share W
    const int bc = blockIdx.x & 31;   // 64-b chunk
    const int bbase = bc * 64;

    // ---- W fragment: lane=i, d in {2w, 2w+1} (32 VGPR) ----
    float wq0[16], wq1[16];
    {
        const int base = (o * 64 + lane) * 256 + w * 32;
        #pragma unroll
        for (int eq = 0; eq < 4; ++eq) {
            if (PRE) {
                const float4 a0 = *reinterpret_cast<const float4*>(rw + base + eq * 4);
                wq0[4*eq+0] = a0.x;  wq0[4*eq+1] = a0.y;
                wq0[4*eq+2] = a0.z;  wq0[4*eq+3] = a0.w;
                const float4 a1 = *reinterpret_cast<const float4*>(rw + base + 16 + eq * 4);
                wq1[4*eq+0] = a1.x;  wq1[4*eq+1] = a1.y;
                wq1[4*eq+2] = a1.z;  wq1[4*eq+3] = a1.w;
            } else {
                const float4 a0 = *reinterpret_cast<const float4*>(rw + base + eq * 4);
                const float4 n0 = *reinterpret_cast<const float4*>(ns + base + eq * 4);
                wq0[4*eq+0] = a0.x + n0.x;  wq0[4*eq+1] = a0.y + n0.y;
                wq0[4*eq+2] = a0.z + n0.z;  wq0[4*eq+3] = a0.w + n0.w;
                const float4 a1 = *reinterpret_cast<const float4*>(rw + base + 16 + eq * 4);
                const float4 n1 = *reinterpret_cast<const float4*>(ns + base + 16 + eq * 4);
                wq1[4*eq+0] = a1.x + n1.x;  wq1[4*eq+1] = a1.y + n1.y;
                wq1[4*eq+2] = a1.z + n1.z;  wq1[4*eq+3] = a1.w + n1.w;
            }
        }
    }

    // ---- precomputed LDS addresses (R12-verified patterns) ----
    const int d0 = 2 * w, d1 = 2 * w + 1;
    float* pw0 = lds + d0 * 64 + ((((lane >> 2) ^ (d0 & 7)) << 2) | (lane & 3));
    float* pw1 = lds + d1 * 64 + ((((lane >> 2) ^ (d1 & 7)) << 2) | (lane & 3));

    const int qB  = lane >> 4;      // i-quarter 0..3
    const int dB  = lane & 15;
    const int swz = dB & 7;
    const float4* prbase = reinterpret_cast<const float4*>(lds) + (w * 16 + dB) * 16;
    const float4* pr0 = prbase + ((4 * qB + 0) ^ swz);
    const float4* pr1 = prbase + ((4 * qB + 1) ^ swz);
    const float4* pr2 = prbase + ((4 * qB + 2) ^ swz);
    const float4* pr3 = prbase + ((4 * qB + 3) ^ swz);

    // x_t reads (A-phase): lane = i; base quad-skewed by i>>3
    const float* xrb = xlds + lane * 16 + ((lane >> 3) << 2);

    // x_t writes (staging): thread holds (b=w, e=4k+ih, i=4il+m)
    const int il = lane & 15, ih = lane >> 4;
    float* xwb = xlds + w * 1056 + il * 64 + ((il >> 1) << 2) + ih;
    float* xw0 = xwb + 0;
    float* xw1 = xwb + 4;
    float* xw2 = xwb + 8;
    float* xw3 = xwb + 12;

    const float4* xsrc0 = reinterpret_cast<const float4*>(x) + bbase * 256
                        + (w * 256 + lane);

    const int outbase = (o * 2048 + bbase + w) * 16 + dB;

    // ---- prologue: stage x-tile 0 (transposed+skewed) ----
    float4 xb0 = xsrc0[0];
    float4 xb1 = xsrc0[64];
    float4 xb2 = xsrc0[128];
    float4 xb3 = xsrc0[192];
    xw0[0] = xb0.x;  xw0[16] = xb0.y;  xw0[32] = xb0.z;  xw0[48] = xb0.w;
    xw1[0] = xb1.x;  xw1[16] = xb1.y;  xw1[32] = xb1.z;  xw1[48] = xb1.w;
    xw2[0] = xb2.x;  xw2[16] = xb2.y;  xw2[32] = xb2.z;  xw2[48] = xb2.w;
    xw3[0] = xb3.x;  xw3[16] = xb3.y;  xw3[32] = xb3.z;  xw3[48] = xb3.w;
    __syncthreads();                // x-tile 0 ready

    #pragma unroll
    for (int s = 0; s < 8; ++s) {
        // ---- A-phase: x_t -> p (8 b's, 4 conflict-free b128 reads each) ----
        #pragma unroll
        for (int bb = 0; bb < 8; ++bb) {
            const float4 v0 = *reinterpret_cast<const float4*>(xrb + bb * 1056 + 0);
            const float4 v1 = *reinterpret_cast<const float4*>(xrb + bb * 1056 + 4);
            const float4 v2 = *reinterpret_cast<const float4*>(xrb + bb * 1056 + 8);
            const float4 v3 = *reinterpret_cast<const float4*>(xrb + bb * 1056 + 12);
            float a0 = 0.f, a1 = 0.f;
            a0 = fmaf(wq0[0],  v0.x, a0);  a1 = fmaf(wq1[0],  v0.x, a1);
            a0 = fmaf(wq0[1],  v0.y, a0);  a1 = fmaf(wq1[1],  v0.y, a1);
            a0 = fmaf(wq0[2],  v0.z, a0);  a1 = fmaf(wq1[2],  v0.z, a1);
            a0 = fmaf(wq0[3],  v0.w, a0);  a1 = fmaf(wq1[3],  v0.w, a1);
            a0 = fmaf(wq0[4],  v1.x, a0);  a1 = fmaf(wq1[4],  v1.x, a1);
            a0 = fmaf(wq0[5],  v1.y, a0);  a1 = fmaf(wq1[5],  v1.y, a1);
            a0 = fmaf(wq0[6],  v1.z, a0);  a1 = fmaf(wq1[6],  v1.z, a1);
            a0 = fmaf(wq0[7],  v1.w, a0);  a1 = fmaf(wq1[7],  v1.w, a1);
            a0 = fmaf(wq0[8],  v2.x, a0);  a1 = fmaf(wq1[8],  v2.x, a1);
            a0 = fmaf(wq0[9],  v2.y, a0);  a1 = fmaf(wq1[9],  v2.y, a1);
            a0 = fmaf(wq0[10], v2.z, a0);  a1 = fmaf(wq1[10], v2.z, a1);
            a0 = fmaf(wq0[11], v2.w, a0);  a1 = fmaf(wq1[11], v2.w, a1);
            a0 = fmaf(wq0[12], v3.x, a0);  a1 = fmaf(wq1[12], v3.x, a1);
            a0 = fmaf(wq0[13], v3.y, a0);  a1 = fmaf(wq1[13], v3.y, a1);
            a0 = fmaf(wq0[14], v3.z, a0);  a1 = fmaf(wq1[14], v3.z, a1);
            a0 = fmaf(wq0[15], v3.w, a0);  a1 = fmaf(wq1[15], v3.w, a1);
            pw0[bb * 1024] = a0;
            pw1[bb * 1024] = a1;
        }
        __syncthreads();            // p ready; x_t free

        // ---- B-read: p[16] (i = qB*16 + 4jj + m) ----
        float p[16];
        {
            const float4 v0 = *pr0, v1 = *pr1, v2 = *pr2, v3 = *pr3;
            p[0]=v0.x; p[1]=v0.y; p[2]=v0.z; p[3]=v0.w;
            p[4]=v1.x; p[5]=v1.y; p[6]=v1.z; p[7]=v1.w;
            p[8]=v2.x; p[9]=v2.y; p[10]=v2.z; p[11]=v2.w;
            p[12]=v3.x; p[13]=v3.y; p[14]=v3.z; p[15]=v3.w;
        }

        // ---- T14 issue-early: next x-tile global loads ----
        if (s < 7) {
            const float4* xsrc = xsrc0 + (s + 1) * 2048;
            xb0 = xsrc[0];  xb1 = xsrc[64];  xb2 = xsrc[128];  xb3 = xsrc[192];
        }

        // ---- routing iterations ----
        float t0 = (p[0]+p[1]) + (p[2]+p[3]);
        float t1 = (p[4]+p[5]) + (p[6]+p[7]);
        float t2 = (p[8]+p[9]) + (p[10]+p[11]);
        float t3 = (p[12]+p[13]) + (p[14]+p[15]);
        float part = (t0 + t1) + (t2 + t3);
        part += __shfl_xor(part, 16);
        part += __shfl_xor(part, 32);
        float sv = part * (1.0f / 64.0f);

        float sn = sv * sv;         // squash norm over d (16-lane groups)
        sn += __shfl_xor(sn, 1); sn += __shfl_xor(sn, 2);
        sn += __shfl_xor(sn, 4); sn += __shfl_xor(sn, 8);
        float factor = __builtin_amdgcn_sqrtf(sn)
                     * __builtin_amdgcn_rcpf(1.0f + sn);
        float Vsum = sv * factor;

        #pragma unroll
        for (int it = 0; it < 2; ++it) {
            const float c = Vsum * 1.44269504089f;      // log2(e)
            float e0, e1, e2, e3;
            float dd0, dd1, dd2, dd3, nn0, nn1, nn2, nn3;
            e0 = __builtin_amdgcn_exp2f(p[0] * c);
            e1 = __builtin_amdgcn_exp2f(p[1] * c);
            e2 = __builtin_amdgcn_exp2f(p[2] * c);
            e3 = __builtin_amdgcn_exp2f(p[3] * c);
            dd0 = e0; dd1 = e1; dd2 = e2; dd3 = e3;
            nn0 = e0 * p[0]; nn1 = e1 * p[1]; nn2 = e2 * p[2]; nn3 = e3 * p[3];
            e0 = __builtin_amdgcn_exp2f(p[4] * c);
            e1 = __builtin_amdgcn_exp2f(p[5] * c);
            e2 = __builtin_amdgcn_exp2f(p[6] * c);
            e3 = __builtin_amdgcn_exp2f(p[7] * c);
            dd0 += e0; dd1 += e1; dd2 += e2; dd3 += e3;
            nn0 = fmaf(e0, p[4], nn0); nn1 = fmaf(e1, p[5], nn1);
            nn2 = fmaf(e2, p[6], nn2); nn3 = fmaf(e3, p[7], nn3);
            e0 = __builtin_amdgcn_exp2f(p[8] * c);
            e1 = __builtin_amdgcn_exp2f(p[9] * c);
            e2 = __builtin_amdgcn_exp2f(p[10] * c);
            e3 = __builtin_amdgcn_exp2f(p[11] * c);
            dd0 += e0; dd1 += e1; dd2 += e2; dd3 += e3;
            nn0 = fmaf(e0, p[8], nn0);  nn1 = fmaf(e1, p[9], nn1);
            nn2 = fmaf(e2, p[10], nn2); nn3 = fmaf(e3, p[11], nn3);
            e0 = __builtin_amdgcn_exp2f(p[12] * c);
            e1 = __builtin_amdgcn_exp2f(p[13] * c);
            e2 = __builtin_amdgcn_exp2f(p[14] * c);
            e3 = __builtin_amdgcn_exp2f(p[15] * c);
            dd0 += e0; dd1 += e1; dd2 += e2; dd3 += e3;
            nn0 = fmaf(e0, p[12], nn0); nn1 = fmaf(e1, p[13], nn1);
            nn2 = fmaf(e2, p[14], nn2); nn3 = fmaf(e3, p[15], nn3);

            float den = (dd0 + dd1) + (dd2 + dd3);
            float num = (nn0 + nn1) + (nn2 + nn3);
            den += __shfl_xor(den, 16); den += __shfl_xor(den, 32);
            num += __shfl_xor(num, 16); num += __shfl_xor(num, 32);
            sv = num * __builtin_amdgcn_rcpf(den);
            sn = sv * sv;
            sn += __shfl_xor(sn, 1); sn += __shfl_xor(sn, 2);
            sn += __shfl_xor(sn, 4); sn += __shfl_xor(sn, 8);
            factor = __builtin_amdgcn_sqrtf(sn)
                   * __builtin_amdgcn_rcpf(1.0f + sn);
            Vsum += sv * factor;
        }

        if (qB == 0)
            out[outbase + s * 128] = sv * factor;       // (1,O,B,DO), b=+8 per s

        // ---- T14 write-late: store next x-tile (transposed+skewed) ----
        if (s < 7) {
            xw0[0] = xb0.x;  xw0[16] = xb0.y;  xw0[32] = xb0.z;  xw0[48] = xb0.w;
            xw1[0] = xb1.x;  xw1[16] = xb1.y;  xw1[32] = xb1.z;  xw1[48] = xb1.w;
            xw2[0] = xb2.x;  xw2[16] = xb2.y;  xw2[32] = xb2.z;  xw2[48] = xb2.w;
            xw3[0] = xb3.x;  xw3[16] = xb3.y;  xw3[32] = xb3.z;  xw3[48] = xb3.w;
        }
        __syncthreads();            // p-reads done & next x-tile ready
    }
}

extern "C" void kernel_launch(void* const* d_in, const int* in_sizes, int n_in,
                              void* d_out, int out_size, void* d_ws, size_t ws_size,
                              hipStream_t stream) {
    const float* x  = (const float*)d_in[0];
    const float* rw = (const float*)d_in[1];
    const float* ns = (const float*)d_in[2];
    float* out = (float*)d_out;
    (void)in_sizes; (void)n_in; (void)out_size;

    const int grid = 32 * 32;       // blockIdx = o*32 + bc (64 b per block)
    const size_t w2_bytes = 32u * 64u * 16u * 16u * sizeof(float);  // 2 MB

    if (ws_size >= w2_bytes) {
        float* w2 = (float*)d_ws;
        wsum_kernel<<<512, 256, 0, stream>>>(rw, ns, w2);
        routing_kernel<true><<<grid, THREADS, 66560, stream>>>(x, w2, ns, out);
    } else {
        routing_kernel<false><<<grid, THREADS, 66560, stream>>>(x, rw, ns, out);
    }
}